// Round 19
// baseline (135.420 us; speedup 1.0000x reference)
//
#include <hip/hip_runtime.h>

// GraphSAGE mean aggregator on MI355X.
// hn = segment_mean(fb[src], dst);  out = fb@W_self + hn@W_neigh + biases
// R2-R18: CSR gather-side reduction, bf16 MFMA K=256 (fb|hn), wide gather
// (4 nodes/wave, 16-lane groups, depth-8 uint4), XCD-partitioned fill,
// fused scan, no-LDS mm.
// R19: gather+mm merged into ONE kernel, fixing R12's two failure causes:
//      (a) wide gather (8 iters x 4 nodes/wave, not 32 serial), (b) hn via
//      GLOBAL not LDS — block writes its own 128 hn rows (3.2MB/XCD, fits
//      per-XCD 4MB L2), __syncthreads, mm reads them back L2-local. No LDS
//      -> no occupancy cap; hn HBM round-trip + one launch gap eliminated.

constexpr int N_NODES = 100000;
constexpr int N_EDGES = 640000;
constexpr int D = 128;

constexpr int SCAN_NBLOCKS = 98;     // 98 x 1024 elems covers 100000

constexpr int NXCD = 8;
constexpr int XRANGE = (N_NODES + NXCD - 1) / NXCD;        // 12500
constexpr int FILL_BPG = 250;        // blocks per XCD-group
constexpr int FILL_EPB = N_EDGES / FILL_BPG;               // 2560 edges/block

typedef __attribute__((ext_vector_type(8))) short bf16x8;
typedef __attribute__((ext_vector_type(4))) float f32x4;

__device__ __forceinline__ unsigned short f2bf(float f) {
    unsigned int u = __float_as_uint(f);
    unsigned int r = u + 0x7FFFu + ((u >> 16) & 1u);   // round-to-nearest-even
    return (unsigned short)(r >> 16);
}
__device__ __forceinline__ float bflo(unsigned int v) { return __uint_as_float(v << 16); }
__device__ __forceinline__ float bfhi(unsigned int v) { return __uint_as_float(v & 0xFFFF0000u); }

// ---- zero deg + ctr + weight packing (128 blocks x 256 = 32768 threads) ----
// wp flat index i = (((m*4+ks)*4+h)*128 + c)*8 + r  holds  bf16(W_m[ks*32+h*8+r][c])
// Same (h,r)->k map as the A-fragment build in gathermm (shared k-permutation).
__global__ __launch_bounds__(256) void zero_kernel(int4* __restrict__ deg4,
                                                   int* __restrict__ ctr,
                                                   const float* __restrict__ Ws,
                                                   const float* __restrict__ Wn,
                                                   unsigned short* __restrict__ wp) {
    const int gid = blockIdx.x * 256 + threadIdx.x;
    if (gid < N_NODES / 4) deg4[gid] = int4{0, 0, 0, 0};
    if (gid == 0) ctr[0] = 0;
    {   // 2*D*D = 32768 == grid size: exactly one element each
        int i = gid;
        int r  = i & 7;
        int c  = (i >> 3) & 127;
        int h  = (i >> 10) & 3;
        int ks = (i >> 12) & 3;
        int m  = i >> 14;
        const float* W = m ? Wn : Ws;
        int k = ks * 32 + h * 8 + r;
        wp[i] = f2bf(W[k * D + c]);
    }
}

// ------------- prepass: deg atomics + feat->bf16 (NT feat reads) -------------
__global__ void prepass_kernel(const int* __restrict__ dst, int* __restrict__ deg,
                               const float* __restrict__ feat,
                               unsigned short* __restrict__ fb) {
    const int gid = blockIdx.x * blockDim.x + threadIdx.x;   // 640K threads
    if (gid < N_EDGES) atomicAdd(&deg[dst[gid]], 1);
    const int total4 = N_NODES * D / 4;
    const f32x4* fv = (const f32x4*)feat;
    for (int i = gid; i < total4; i += N_EDGES) {
        f32x4 v = __builtin_nontemporal_load(&fv[i]);   // read-once stream
        ushort4 o;
        o.x = f2bf(v.x); o.y = f2bf(v.y); o.z = f2bf(v.z); o.w = f2bf(v.w);
        ((ushort4*)fb)[i] = o;
    }
}

// ---------------- fused scan: partial sums + grid barrier + rowptr/cursor ----
// 98 blocks (all co-resident on 256 CUs), scan-only work. ctr zeroed by zero_kernel.
__global__ __launch_bounds__(256) void scan_kernel(const int* __restrict__ deg,
                                                   int* __restrict__ rowptr,
                                                   int* __restrict__ cursor,
                                                   int* __restrict__ bsum,
                                                   int* __restrict__ ctr) {
    __shared__ int wsum[4];
    const int tid = threadIdx.x;
    const int lane = tid & 63;
    const int wave = tid >> 6;
    const int base = (blockIdx.x * 256 + tid) * 4;

    int local[4];
    int tsum = 0;
    #pragma unroll
    for (int j = 0; j < 4; j++) {
        int idx = base + j;
        local[j] = (idx < N_NODES) ? deg[idx] : 0;
        tsum += local[j];
    }
    // Phase 1: publish per-block sum.
    {
        int s = tsum;
        for (int off = 32; off > 0; off >>= 1) s += __shfl_down(s, off, 64);
        if (lane == 0) wsum[wave] = s;
        __syncthreads();
        if (tid == 0) bsum[blockIdx.x] = wsum[0] + wsum[1] + wsum[2] + wsum[3];
    }
    // Grid barrier.
    __syncthreads();
    if (tid == 0) {
        __threadfence();
        __hip_atomic_fetch_add(ctr, 1, __ATOMIC_ACQ_REL, __HIP_MEMORY_SCOPE_AGENT);
        while (__hip_atomic_load(ctr, __ATOMIC_ACQUIRE, __HIP_MEMORY_SCOPE_AGENT)
               < SCAN_NBLOCKS) {}
    }
    __syncthreads();

    // Phase 2: block offset (redundant per block), intra-block scan, write.
    int v = (tid < blockIdx.x) ? bsum[tid] : 0;     // blockIdx.x < 98 <= 256
    for (int off = 32; off > 0; off >>= 1) v += __shfl_down(v, off, 64);
    if (lane == 0) wsum[wave] = v;
    __syncthreads();
    const int boff = wsum[0] + wsum[1] + wsum[2] + wsum[3];
    __syncthreads();

    int incl = tsum;
    for (int off = 1; off < 64; off <<= 1) {
        int u = __shfl_up(incl, off, 64);
        if (lane >= off) incl += u;
    }
    if (lane == 63) wsum[wave] = incl;
    __syncthreads();
    int woff = 0;
    for (int w = 0; w < 4; w++) woff += (w < wave) ? wsum[w] : 0;

    int run = boff + woff + (incl - tsum);
    #pragma unroll
    for (int j = 0; j < 4; j++) {
        int idx = base + j;
        if (idx < N_NODES) {
            rowptr[idx] = run;
            cursor[idx] = run;
            run += local[j];
        }
    }
    if (blockIdx.x == 0 && tid == 0) rowptr[N_NODES] = N_EDGES;
}

// ---- fill: XCD-partitioned counting-sort scatter (R18, kept) ----
__global__ __launch_bounds__(256) void fill_kernel(const int* __restrict__ src,
                                                   const int* __restrict__ dst,
                                                   int* __restrict__ cursor,
                                                   int* __restrict__ csr_src) {
    const int xcd = blockIdx.x & (NXCD - 1);
    const int j   = blockIdx.x >> 3;                 // 0..249
    const int lo  = xcd * XRANGE;
    const int hi  = lo + XRANGE;
    const int ebase = j * FILL_EPB;

    for (int e = ebase + threadIdx.x; e < ebase + FILL_EPB; e += 256) {
        const int d = dst[e];
        const int s = src[e];
        if (d >= lo && d < hi) {
            int pos = atomicAdd(&cursor[d], 1);
            csr_src[pos] = s;                        // cached store (L2-local)
        }
    }
}

// ---- gathermm: wide gather of own 128 rows -> hn (global, L2-local) ----
// ---- then __syncthreads -> K=256 MFMA over [fb|hn] of the same rows ----
__global__ __launch_bounds__(256) void gathermm_kernel(
    const unsigned short* __restrict__ fb, const int* __restrict__ csr_src,
    const int* __restrict__ rowptr, const unsigned short* __restrict__ wp,
    const float* __restrict__ b_self, const float* __restrict__ b_neigh,
    unsigned short* __restrict__ hn, float* __restrict__ out)
{
    const int tid = threadIdx.x;
    const int wave = tid >> 6, lane = tid & 63;
    const int g = lane >> 4;          // group 0..3
    const int gl = lane & 15;         // lane within group
    const int row_base = blockIdx.x * 128;

    // ---- Phase 1: wide gather, wave w covers 32 nodes as 8 iters x 4 nodes ----
    for (int it = 0; it < 8; it++) {
        const int n = row_base + wave * 32 + it * 4 + g;
        if (n < N_NODES) {
            const int e0 = rowptr[n];
            const int e1 = rowptr[n + 1];
            float acc[8] = {0.f, 0.f, 0.f, 0.f, 0.f, 0.f, 0.f, 0.f};
            for (int base = e0; base < e1; base += 8) {
                int sidx[8];
                #pragma unroll
                for (int j = 0; j < 8; j++) {
                    int ee = base + j;
                    ee = (ee < e1) ? ee : (e1 - 1);      // clamp, no branch
                    sidx[j] = csr_src[ee];
                }
                uint4 v[8];
                #pragma unroll
                for (int j = 0; j < 8; j++)
                    v[j] = ((const uint4*)(fb + (size_t)sidx[j] * D))[gl];
                #pragma unroll
                for (int j = 0; j < 8; j++) {
                    const float w = (base + j < e1) ? 1.0f : 0.0f;
                    acc[0] = fmaf(w, bflo(v[j].x), acc[0]);
                    acc[1] = fmaf(w, bfhi(v[j].x), acc[1]);
                    acc[2] = fmaf(w, bflo(v[j].y), acc[2]);
                    acc[3] = fmaf(w, bfhi(v[j].y), acc[3]);
                    acc[4] = fmaf(w, bflo(v[j].z), acc[4]);
                    acc[5] = fmaf(w, bfhi(v[j].z), acc[5]);
                    acc[6] = fmaf(w, bflo(v[j].w), acc[6]);
                    acc[7] = fmaf(w, bfhi(v[j].w), acc[7]);
                }
            }
            const float sc = 1.0f / (float)max(e1 - e0, 1);
            uint4 o;
            o.x = ((unsigned int)f2bf(acc[1] * sc) << 16) | (unsigned int)f2bf(acc[0] * sc);
            o.y = ((unsigned int)f2bf(acc[3] * sc) << 16) | (unsigned int)f2bf(acc[2] * sc);
            o.z = ((unsigned int)f2bf(acc[5] * sc) << 16) | (unsigned int)f2bf(acc[4] * sc);
            o.w = ((unsigned int)f2bf(acc[7] * sc) << 16) | (unsigned int)f2bf(acc[6] * sc);
            ((uint4*)(hn + (size_t)n * D))[gl] = o;      // stays in this XCD's L2
        }
    }
    __syncthreads();

    // ---- Phase 2: K=256 MFMA; hn rows just written by THIS block (L2-hot) ----
    const int h = lane >> 4, c = lane & 15;
    const int wrow_base = row_base + wave * 32;

    bf16x8 a[2][2][4];
    #pragma unroll
    for (int ti = 0; ti < 2; ti++) {
        int row = wrow_base + ti * 16 + c;
        int rowc = min(row, N_NODES - 1);             // clamp stays in-block; stores guarded
        const bf16x8* f0 = (const bf16x8*)(fb + (size_t)rowc * D);
        const bf16x8* f1 = (const bf16x8*)(hn + (size_t)rowc * D);
        #pragma unroll
        for (int ks = 0; ks < 4; ks++) {
            a[0][ti][ks] = f0[ks * 4 + h];
            a[1][ti][ks] = f1[ks * 4 + h];
        }
    }

    const bf16x8* wpv = (const bf16x8*)wp;
    for (int ct = 0; ct < 8; ct++) {
        f32x4 acc[2];
        #pragma unroll
        for (int ti = 0; ti < 2; ti++) acc[ti] = f32x4{0.f, 0.f, 0.f, 0.f};

        #pragma unroll
        for (int m = 0; m < 2; m++) {
            bf16x8 b[4];
            #pragma unroll
            for (int ks = 0; ks < 4; ks++)
                b[ks] = wpv[((m * 4 + ks) * 4 + h) * 128 + ct * 16 + c];
            #pragma unroll
            for (int ks = 0; ks < 4; ks++)
                #pragma unroll
                for (int ti = 0; ti < 2; ti++)
                    acc[ti] = __builtin_amdgcn_mfma_f32_16x16x32_bf16(a[m][ti][ks], b[ks], acc[ti], 0, 0, 0);
        }

        const int col = ct * 16 + c;
        const float bias = b_self[col] + b_neigh[col];
        #pragma unroll
        for (int ti = 0; ti < 2; ti++) {
            if (wrow_base + ti * 16 < N_NODES) {      // N%16==0: tile guard exact
                #pragma unroll
                for (int q = 0; q < 4; q++) {
                    int row = wrow_base + ti * 16 + h * 4 + q;   // C/D: row=(lane>>4)*4+reg
                    __builtin_nontemporal_store(acc[ti][q] + bias,
                                                &out[(size_t)row * D + col]);
                }
            }
        }
    }
}

extern "C" void kernel_launch(void* const* d_in, const int* in_sizes, int n_in,
                              void* d_out, int out_size, void* d_ws, size_t ws_size,
                              hipStream_t stream) {
    const float* feat    = (const float*)d_in[0];
    const int*   src     = (const int*)d_in[1];
    const int*   dst     = (const int*)d_in[2];
    const float* W_self  = (const float*)d_in[3];
    const float* b_self  = (const float*)d_in[4];
    const float* W_neigh = (const float*)d_in[5];
    const float* b_neigh = (const float*)d_in[6];
    float* out = (float*)d_out;

    // ws layout: fb [N*D bf16] | hn [N*D bf16] | wp [2*D*D bf16] | deg [N] |
    //            rowptr [N+1] | cursor [N] | csr_src [E] | bsum [98] | ctr [1]
    unsigned short* fb = (unsigned short*)d_ws;
    unsigned short* hn = fb + (size_t)N_NODES * D;
    unsigned short* wp = hn + (size_t)N_NODES * D;
    int*   deg     = (int*)(wp + 2 * D * D);
    int*   rowptr  = deg + N_NODES;
    int*   cursor  = rowptr + (N_NODES + 1);
    int*   csr_src = cursor + N_NODES;
    int*   bsum    = csr_src + N_EDGES;
    int*   ctr     = bsum + SCAN_NBLOCKS;

    zero_kernel<<<128, 256, 0, stream>>>((int4*)deg, ctr, W_self, W_neigh, wp);

    prepass_kernel<<<(N_EDGES + 255) / 256, 256, 0, stream>>>(dst, deg, feat, fb);

    scan_kernel<<<SCAN_NBLOCKS, 256, 0, stream>>>(deg, rowptr, cursor, bsum, ctr);

    fill_kernel<<<NXCD * FILL_BPG, 256, 0, stream>>>(src, dst, cursor, csr_src);

    gathermm_kernel<<<(N_NODES + 127) / 128, 256, 0, stream>>>(fb, csr_src, rowptr, wp,
                                                               b_self, b_neigh, hn, out);
}

// Round 20
// 128.182 us; speedup vs baseline: 1.0565x; 1.0565x over previous
//
#include <hip/hip_runtime.h>

// GraphSAGE mean aggregator on MI355X.
// hn = segment_mean(fb[src], dst);  out = fb@W_self + hn@W_neigh + biases
// R2-R13: CSR gather-side reduction, bf16 MFMA K=256 (fb|hn), hn-before-mm
// dataflow, no-LDS mm, fused scan. R15/R16: wide gather (4 nodes/wave, 16-lane
// groups, uint4 slices). R17: gather depth-8.
// R18: XCD-partitioned fill (WRITE amplification 44MB -> ~3MB). BEST: 128.3us.
// R19 (reverted): gather+mm fusion — 3rd confirmation that barrier-coupling a
// latency-bound phase to a throughput phase loses to split kernels (hn wrote
// back to HBM anyway; occupancy 25%; slowest-gather-wave serialization).
// R20: exact revert to R18.

constexpr int N_NODES = 100000;
constexpr int N_EDGES = 640000;
constexpr int D = 128;

constexpr int SCAN_NBLOCKS = 98;     // 98 x 1024 elems covers 100000

constexpr int NXCD = 8;
constexpr int XRANGE = (N_NODES + NXCD - 1) / NXCD;        // 12500
constexpr int FILL_BPG = 250;        // blocks per XCD-group
constexpr int FILL_EPB = N_EDGES / FILL_BPG;               // 2560 edges/block

typedef __attribute__((ext_vector_type(8))) short bf16x8;
typedef __attribute__((ext_vector_type(4))) float f32x4;

__device__ __forceinline__ unsigned short f2bf(float f) {
    unsigned int u = __float_as_uint(f);
    unsigned int r = u + 0x7FFFu + ((u >> 16) & 1u);   // round-to-nearest-even
    return (unsigned short)(r >> 16);
}
__device__ __forceinline__ float bflo(unsigned int v) { return __uint_as_float(v << 16); }
__device__ __forceinline__ float bfhi(unsigned int v) { return __uint_as_float(v & 0xFFFF0000u); }

// ---------------- zero deg (int4-wide, full-width grid) ----------------
__global__ __launch_bounds__(256) void zero_deg_kernel(int4* __restrict__ deg4) {
    int i = blockIdx.x * 256 + threadIdx.x;
    if (i < N_NODES / 4) deg4[i] = int4{0, 0, 0, 0};
}

// ------- prepass: deg atomics + weight packing + feat->bf16 + ctr zero -------
// wp flat index i = (((m*4+ks)*4+h)*128 + c)*8 + r  holds  bf16(W_m[ks*32+h*8+r][c])
// Same (h,r)->k map as the A-fragment build in mmfused (shared k-permutation).
__global__ void prepass_kernel(const int* __restrict__ dst, int* __restrict__ deg,
                               const float* __restrict__ Ws, const float* __restrict__ Wn,
                               unsigned short* __restrict__ wp,
                               const float* __restrict__ feat, unsigned short* __restrict__ fb,
                               int* __restrict__ ctr) {
    const int gid = blockIdx.x * blockDim.x + threadIdx.x;   // 640K threads
    if (gid == 0) ctr[0] = 0;                 // scan grid-barrier counter
    if (gid < N_EDGES) atomicAdd(&deg[dst[gid]], 1);
    if (gid < 2 * D * D) {
        int i = gid;
        int r  = i & 7;
        int c  = (i >> 3) & 127;
        int h  = (i >> 10) & 3;
        int ks = (i >> 12) & 3;
        int m  = i >> 14;
        const float* W = m ? Wn : Ws;
        int k = ks * 32 + h * 8 + r;
        wp[i] = f2bf(W[k * D + c]);
    }
    const int total4 = N_NODES * D / 4;
    for (int i = gid; i < total4; i += N_EDGES) {
        float4 v = ((const float4*)feat)[i];
        ushort4 o;
        o.x = f2bf(v.x); o.y = f2bf(v.y); o.z = f2bf(v.z); o.w = f2bf(v.w);
        ((ushort4*)fb)[i] = o;
    }
}

// ---------------- fused scan: partial sums + grid barrier + rowptr/cursor ----
// 98 blocks (all co-resident on 256 CUs), scan-only work. ctr zeroed by prepass.
__global__ __launch_bounds__(256) void scan_kernel(const int* __restrict__ deg,
                                                   int* __restrict__ rowptr,
                                                   int* __restrict__ cursor,
                                                   int* __restrict__ bsum,
                                                   int* __restrict__ ctr) {
    __shared__ int wsum[4];
    const int tid = threadIdx.x;
    const int lane = tid & 63;
    const int wave = tid >> 6;
    const int base = (blockIdx.x * 256 + tid) * 4;

    int local[4];
    int tsum = 0;
    #pragma unroll
    for (int j = 0; j < 4; j++) {
        int idx = base + j;
        local[j] = (idx < N_NODES) ? deg[idx] : 0;
        tsum += local[j];
    }
    // Phase 1: publish per-block sum.
    {
        int s = tsum;
        for (int off = 32; off > 0; off >>= 1) s += __shfl_down(s, off, 64);
        if (lane == 0) wsum[wave] = s;
        __syncthreads();
        if (tid == 0) bsum[blockIdx.x] = wsum[0] + wsum[1] + wsum[2] + wsum[3];
    }
    // Grid barrier.
    __syncthreads();
    if (tid == 0) {
        __threadfence();
        __hip_atomic_fetch_add(ctr, 1, __ATOMIC_ACQ_REL, __HIP_MEMORY_SCOPE_AGENT);
        while (__hip_atomic_load(ctr, __ATOMIC_ACQUIRE, __HIP_MEMORY_SCOPE_AGENT)
               < SCAN_NBLOCKS) {}
    }
    __syncthreads();

    // Phase 2: block offset (redundant per block), intra-block scan, write.
    int v = (tid < blockIdx.x) ? bsum[tid] : 0;     // blockIdx.x < 98 <= 256
    for (int off = 32; off > 0; off >>= 1) v += __shfl_down(v, off, 64);
    if (lane == 0) wsum[wave] = v;
    __syncthreads();
    const int boff = wsum[0] + wsum[1] + wsum[2] + wsum[3];
    __syncthreads();

    int incl = tsum;
    for (int off = 1; off < 64; off <<= 1) {
        int u = __shfl_up(incl, off, 64);
        if (lane >= off) incl += u;
    }
    if (lane == 63) wsum[wave] = incl;
    __syncthreads();
    int woff = 0;
    for (int w = 0; w < 4; w++) woff += (w < wave) ? wsum[w] : 0;

    int run = boff + woff + (incl - tsum);
    #pragma unroll
    for (int j = 0; j < 4; j++) {
        int idx = base + j;
        if (idx < N_NODES) {
            rowptr[idx] = run;
            cursor[idx] = run;
            run += local[j];
        }
    }
    if (blockIdx.x == 0 && tid == 0) rowptr[N_NODES] = N_EDGES;
}

// ---- fill: XCD-partitioned counting-sort scatter ----
// Block b is on XCD (b&7) under round-robin dispatch; it handles only dsts in
// [xcd*12500, (xcd+1)*12500). Its 250-block group scans all edges (dst/src are
// 5MB -> cache-resident re-reads). All stores to a cursor/csr_src segment come
// from ONE XCD -> lines aggregate in that L2, write back once.
__global__ __launch_bounds__(256) void fill_kernel(const int* __restrict__ src,
                                                   const int* __restrict__ dst,
                                                   int* __restrict__ cursor,
                                                   int* __restrict__ csr_src) {
    const int xcd = blockIdx.x & (NXCD - 1);
    const int j   = blockIdx.x >> 3;                 // 0..249
    const int lo  = xcd * XRANGE;
    const int hi  = lo + XRANGE;                     // last range end >= N_NODES
    const int ebase = j * FILL_EPB;

    for (int e = ebase + threadIdx.x; e < ebase + FILL_EPB; e += 256) {
        const int d = dst[e];
        const int s = src[e];
        if (d >= lo && d < hi) {
            int pos = atomicAdd(&cursor[d], 1);
            csr_src[pos] = s;                        // cached store (L2-local)
        }
    }
}

// ---- gather: 4 nodes/wave, 16-lane groups, depth-8 uint4 row slices ----
// Group g of a wave owns node n; lane gl loads its 16B slice of each edge row.
// Mean deg 6.4 -> ~80% of nodes finish in one batch of 8 parallel row loads.
// 16 nodes per 256-thr block -> grid = N_NODES/16 = 6250 (exact).
__global__ __launch_bounds__(256) void gather_kernel(
    const unsigned short* __restrict__ fb, const int* __restrict__ csr_src,
    const int* __restrict__ rowptr, unsigned short* __restrict__ hn)
{
    const int tid = threadIdx.x;
    const int lane = tid & 63;
    const int g = lane >> 4;          // group 0..3
    const int gl = lane & 15;         // lane within group
    const int wid = (blockIdx.x * blockDim.x + tid) >> 6;   // global wave id
    const int n = wid * 4 + g;        // node for this group
    if (n >= N_NODES) return;

    const int e0 = rowptr[n];
    const int e1 = rowptr[n + 1];

    float acc[8] = {0.f, 0.f, 0.f, 0.f, 0.f, 0.f, 0.f, 0.f};
    for (int base = e0; base < e1; base += 8) {
        int sidx[8];
        #pragma unroll
        for (int j = 0; j < 8; j++) {
            int ee = base + j;
            ee = (ee < e1) ? ee : (e1 - 1);          // clamp, no branch
            sidx[j] = csr_src[ee];
        }
        uint4 v[8];
        #pragma unroll
        for (int j = 0; j < 8; j++)
            v[j] = ((const uint4*)(fb + (size_t)sidx[j] * D))[gl];
        #pragma unroll
        for (int j = 0; j < 8; j++) {
            const float w = (base + j < e1) ? 1.0f : 0.0f;
            acc[0] = fmaf(w, bflo(v[j].x), acc[0]);
            acc[1] = fmaf(w, bfhi(v[j].x), acc[1]);
            acc[2] = fmaf(w, bflo(v[j].y), acc[2]);
            acc[3] = fmaf(w, bfhi(v[j].y), acc[3]);
            acc[4] = fmaf(w, bflo(v[j].z), acc[4]);
            acc[5] = fmaf(w, bfhi(v[j].z), acc[5]);
            acc[6] = fmaf(w, bflo(v[j].w), acc[6]);
            acc[7] = fmaf(w, bfhi(v[j].w), acc[7]);
        }
    }
    const float sc = 1.0f / (float)max(e1 - e0, 1);
    uint4 o;
    o.x = ((unsigned int)f2bf(acc[1] * sc) << 16) | (unsigned int)f2bf(acc[0] * sc);
    o.y = ((unsigned int)f2bf(acc[3] * sc) << 16) | (unsigned int)f2bf(acc[2] * sc);
    o.z = ((unsigned int)f2bf(acc[5] * sc) << 16) | (unsigned int)f2bf(acc[4] * sc);
    o.w = ((unsigned int)f2bf(acc[7] * sc) << 16) | (unsigned int)f2bf(acc[6] * sc);
    ((uint4*)(hn + (size_t)n * D))[gl] = o;          // zero-deg -> 0
}

// ---------------- single K=256 matmul: out = fb@Ws + hn@Wn + bias ------------
// Block = 256 thr = 4 waves, 128 rows. No LDS: W fragments read from global wp
// (64KB, L2/L1-resident broadcast).
__global__ __launch_bounds__(256) void mmfused_kernel(
    const unsigned short* __restrict__ fb, const unsigned short* __restrict__ hn,
    const unsigned short* __restrict__ wp,
    const float* __restrict__ b_self, const float* __restrict__ b_neigh,
    float* __restrict__ out)
{
    const int tid = threadIdx.x;
    const int wave = tid >> 6, lane = tid & 63;
    const int h = lane >> 4, c = lane & 15;
    const int row_base = blockIdx.x * 128 + wave * 32;

    // A fragments: a[m][ti][ks], m=0 -> fb, m=1 -> hn (both bf16 row-major).
    bf16x8 a[2][2][4];
    #pragma unroll
    for (int ti = 0; ti < 2; ti++) {
        int row = row_base + ti * 16 + c;
        int rowc = min(row, N_NODES - 1);             // clamp; stores are guarded
        const bf16x8* f0 = (const bf16x8*)(fb + (size_t)rowc * D);
        const bf16x8* f1 = (const bf16x8*)(hn + (size_t)rowc * D);
        #pragma unroll
        for (int ks = 0; ks < 4; ks++) {
            a[0][ti][ks] = f0[ks * 4 + h];
            a[1][ti][ks] = f1[ks * 4 + h];
        }
    }

    const bf16x8* wpv = (const bf16x8*)wp;
    for (int ct = 0; ct < 8; ct++) {
        f32x4 acc[2];
        #pragma unroll
        for (int ti = 0; ti < 2; ti++) acc[ti] = f32x4{0.f, 0.f, 0.f, 0.f};

        #pragma unroll
        for (int m = 0; m < 2; m++) {
            bf16x8 b[4];
            #pragma unroll
            for (int ks = 0; ks < 4; ks++)
                b[ks] = wpv[((m * 4 + ks) * 4 + h) * 128 + ct * 16 + c];
            #pragma unroll
            for (int ks = 0; ks < 4; ks++)
                #pragma unroll
                for (int ti = 0; ti < 2; ti++)
                    acc[ti] = __builtin_amdgcn_mfma_f32_16x16x32_bf16(a[m][ti][ks], b[ks], acc[ti], 0, 0, 0);
        }

        const int col = ct * 16 + c;
        const float bias = b_self[col] + b_neigh[col];
        #pragma unroll
        for (int ti = 0; ti < 2; ti++) {
            if (row_base + ti * 16 < N_NODES) {       // N%16==0: tile guard exact
                #pragma unroll
                for (int q = 0; q < 4; q++) {
                    int row = row_base + ti * 16 + h * 4 + q;   // C/D: row=(lane>>4)*4+reg
                    __builtin_nontemporal_store(acc[ti][q] + bias,
                                                &out[(size_t)row * D + col]);
                }
            }
        }
    }
}

extern "C" void kernel_launch(void* const* d_in, const int* in_sizes, int n_in,
                              void* d_out, int out_size, void* d_ws, size_t ws_size,
                              hipStream_t stream) {
    const float* feat    = (const float*)d_in[0];
    const int*   src     = (const int*)d_in[1];
    const int*   dst     = (const int*)d_in[2];
    const float* W_self  = (const float*)d_in[3];
    const float* b_self  = (const float*)d_in[4];
    const float* W_neigh = (const float*)d_in[5];
    const float* b_neigh = (const float*)d_in[6];
    float* out = (float*)d_out;

    // ws layout: fb [N*D bf16] | hn [N*D bf16] | wp [2*D*D bf16] | deg [N] |
    //            rowptr [N+1] | cursor [N] | csr_src [E] | bsum [98] | ctr [1]
    unsigned short* fb = (unsigned short*)d_ws;
    unsigned short* hn = fb + (size_t)N_NODES * D;
    unsigned short* wp = hn + (size_t)N_NODES * D;
    int*   deg     = (int*)(wp + 2 * D * D);
    int*   rowptr  = deg + N_NODES;
    int*   cursor  = rowptr + (N_NODES + 1);
    int*   csr_src = cursor + N_NODES;
    int*   bsum    = csr_src + N_EDGES;
    int*   ctr     = bsum + SCAN_NBLOCKS;

    zero_deg_kernel<<<(N_NODES / 4 + 255) / 256, 256, 0, stream>>>((int4*)deg);

    prepass_kernel<<<(N_EDGES + 255) / 256, 256, 0, stream>>>(dst, deg, W_self, W_neigh,
                                                              wp, feat, fb, ctr);

    scan_kernel<<<SCAN_NBLOCKS, 256, 0, stream>>>(deg, rowptr, cursor, bsum, ctr);

    fill_kernel<<<NXCD * FILL_BPG, 256, 0, stream>>>(src, dst, cursor, csr_src);

    // 16 nodes per block -> 6250 blocks exactly.
    gather_kernel<<<N_NODES / 16, 256, 0, stream>>>(fb, csr_src, rowptr, hn);

    mmfused_kernel<<<(N_NODES + 127) / 128, 256, 0, stream>>>(fb, hn, wp, b_self, b_neigh, out);
}